// Round 9
// baseline (531.813 us; speedup 1.0000x reference)
//
#include <hip/hip_runtime.h>
#include <hip/hip_bf16.h>
#include <cfloat>
#include <climits>

#define BS   32
#define NQ   300
#define NC   8192
#define NOBJ 64
#define NROW (BS * NQ)   // 9600
#define CPL  5           // cols per lane: lanes 0..59 own 5 contiguous cols
#define LPAD 65          // padded LDS row stride (words) for [j][t] cost tile
#define PBLK (NROW / 4)  // 2400 producer blocks (4 rows each)

// ---------------------------------------------------------------------------
// helpers (f32 cross-lane: 1 readlane / 1 DPP per step)
// ---------------------------------------------------------------------------
__device__ __forceinline__ float bcast_f32(float v, int lane) {
    union { float f; int i; } c, r;
    c.f = v;
    r.i = __builtin_amdgcn_readlane(c.i, lane);
    return r.f;
}

template <int CTRL>
__device__ __forceinline__ float dpp_min_step_f32(float x) {
    union { float f; int i; } c, r;
    c.f = x;
    r.i = __builtin_amdgcn_update_dpp(c.i, c.i, CTRL, 0xF, 0xF, false);
    return fminf(x, r.f);
}

// full-wave64 min: result valid in lane 63 (validated rounds 3-8, absmax 0)
__device__ __forceinline__ float wave_min_f32(float x) {
    x = dpp_min_step_f32<0x111>(x);  // row_shr:1
    x = dpp_min_step_f32<0x112>(x);  // row_shr:2
    x = dpp_min_step_f32<0x114>(x);  // row_shr:4
    x = dpp_min_step_f32<0x118>(x);  // row_shr:8
    x = dpp_min_step_f32<0x142>(x);  // row_bcast:15
    x = dpp_min_step_f32<0x143>(x);  // row_bcast:31
    return x;
}

// compile-time-index select over a 5-reg int array (stays in VGPRs)
__device__ __forceinline__ int sel5(const int (&a)[CPL], int k) {
    int r = a[0];
    r = (k == 1) ? a[1] : r;
    r = (k == 2) ? a[2] : r;
    r = (k == 3) ? a[3] : r;
    r = (k == 4) ? a[4] : r;
    return r;
}

// ---------------------------------------------------------------------------
// Fused kernel: blocks 0..31 = consumers (one JV matcher per batch, spinning
// on per-batch ready flags); blocks 32..2431 = producers (logZ + cost rows).
// Consumers are first in dispatch order so they're resident from t=0.
// Producers never wait -> no deadlock regardless of scheduling.
// ---------------------------------------------------------------------------
__global__ __launch_bounds__(256) void fused_kernel(const float* __restrict__ x,
                                                    const int* __restrict__ labels,
                                                    float* __restrict__ logZ,
                                                    float* __restrict__ costQ,
                                                    double* __restrict__ partial,
                                                    int* __restrict__ ready,   // [BS]
                                                    int* __restrict__ done,    // [1]
                                                    float* __restrict__ out) {
    __shared__ float cst[NQ * LPAD];   // 78 KB (consumer)
    __shared__ int   col_owner[NQ];    // (consumer)
    __shared__ int   tgt_sh[4][NOBJ];  // (producer)

    int tid  = threadIdx.x;
    int lane = tid & 63;
    int wid  = tid >> 6;

    if (blockIdx.x >= BS) {
        // ================= PRODUCER: logZ + cost for 4 rows =================
        int pbid = blockIdx.x - BS;
        int row  = pbid * 4 + wid;
        int b    = row / NQ;            // == pbid / 75

        // wave-local compact of this batch's labels (order-preserving)
        int lab = labels[b * NOBJ + lane];
        unsigned long long mask = __ballot(lab != 0);
        int nb  = __popcll(mask);
        int pos = __popcll(mask & ((1ull << lane) - 1ull));
        if (lab != 0) tgt_sh[wid][pos] = lab;   // own wave's slice

        // gather target logits first (hides under the stream)
        float xv_g = 0.f;
        if (lane < nb) {
            int cls = tgt_sh[wid][lane];
            xv_g = x[(size_t)row * NC + cls];
        }

        const float4* p = (const float4*)(x + (size_t)row * NC);
        float s0 = 0.f, s1 = 0.f, s2 = 0.f, s3 = 0.f;
        #pragma unroll 8
        for (int k = 0; k < NC / 4 / 64; ++k) {   // 32 float4 per lane
            float4 v = p[lane + k * 64];
            s0 += __expf(v.x);
            s1 += __expf(v.y);
            s2 += __expf(v.z);
            s3 += __expf(v.w);
        }
        float s = (s0 + s1) + (s2 + s3);
        for (int off = 32; off; off >>= 1)
            s += __shfl_xor(s, off);
        float lz = logf(s);
        if (lane == 0) logZ[row] = lz;

        float c = (lane < nb) ? -__expf(xv_g - lz) : 0.f;
        costQ[(size_t)row * NOBJ + lane] = c;

        // release: all 4 waves' global writes drained (vmcnt0 at barrier),
        // then device fence, then one flag increment per block.
        __syncthreads();
        __threadfence();
        if (tid == 0) atomicAdd(&ready[b], 1);
        return;
    }

    // ==================== CONSUMER: JV matcher for batch b ==================
    int b = blockIdx.x;

    // pre-spin setup
    int lab = 0, n = 0;
    if (wid == 0) {
        lab = labels[b * NOBJ + lane];
        n   = __popcll(__ballot(lab != 0));
    }
    for (int j = tid; j < NQ; j += 256) col_owner[j] = INT_MAX;

    // acquire: wait for all 75 producer blocks of this batch
    if (tid == 0) {
        while (__hip_atomic_load(&ready[b], __ATOMIC_ACQUIRE,
                                 __HIP_MEMORY_SCOPE_AGENT) < 75)
            __builtin_amdgcn_s_sleep(2);
    }
    __syncthreads();
    __threadfence();

    // stage costQ -> LDS transpose-pad with all 256 threads
    {
        const float4* src = (const float4*)(costQ + (size_t)b * NQ * NOBJ);
        #pragma unroll
        for (int t = 0; t < 19; ++t) {   // 19*256 >= 4800
            int idx = tid + t * 256;
            if (idx < NQ * NOBJ / 4) {
                float4 v = src[idx];
                int e  = 4 * idx;
                int j  = e >> 6;        // query index
                int t0 = e & 63;        // target index (multiple of 4)
                float* d = &cst[j * LPAD + t0];
                d[0] = v.x; d[1] = v.y; d[2] = v.z; d[3] = v.w;
            }
        }
    }
    __syncthreads();
    if (wid != 0) return;               // solver is wave 0 only; no barriers below

    const int  jbase    = lane * CPL + 1;
    const bool haveCols = (lane < 60);

    // ---- row reduction: lane L = row L+1; u = min_j cost[row][j] ----------
    float rmin = INFINITY;
    int   rarg = 0;
    if (lane < n) {
        #pragma unroll 4
        for (int j = 0; j < NQ; ++j) {
            float cv = cst[j * LPAD + lane];
            if (cv < rmin) { rmin = cv; rarg = j; }   // first-index on ties
        }
    }
    float u_val = (lane < n) ? rmin : 0.f;

    // ---- greedy seeding (wave-local LDS atomics; in-wave ordering) --------
    if (lane < n) atomicMin(&col_owner[rarg], lane);
    bool won = (lane < n) && (col_owner[rarg] == lane);
    if ((lane < n) && !won) atomicCAS(&col_owner[rarg], lane, INT_MAX);

    float v_r[CPL], minv_r[CPL];
    int   p_r[CPL], way_r[CPL];
    #pragma unroll
    for (int k = 0; k < CPL; ++k) {
        v_r[k] = 0.f; way_r[k] = 0;
        int own = haveCols ? col_owner[jbase - 1 + k] : INT_MAX;
        p_r[k] = (own != INT_MAX) ? own + 1 : 0;
    }

    unsigned long long todo = __ballot((lane < n) && !won);

    while (todo) {
        int i = (int)__ffsll(todo);        // row index (1-based)
        todo &= todo - 1;

        #pragma unroll
        for (int k = 0; k < CPL; ++k) minv_r[k] = INFINITY;
        int  usedbits = 0;
        bool inTree   = (lane == i - 1);   // virtual col 0: p[0]=i
        int  i0 = i, j0 = 0, jfin;
        float ui0 = bcast_f32(u_val, i - 1);

        while (true) {
            // 1. issue LDS loads ASAP (addresses depend only on i0)
            int cbase = i0 - 1;
            float ld[CPL];
            #pragma unroll
            for (int k = 0; k < CPL; ++k)
                ld[k] = cst[(jbase - 1 + k) * LPAD + cbase];

            // 2. scan: update minv, track per-lane (lv, kmin); k asc = first-j
            float lv = INFINITY;
            int   kmin = 0;
            if (haveCols) {
                #pragma unroll
                for (int k = 0; k < CPL; ++k) {
                    if (!((usedbits >> k) & 1)) {
                        float cur = ld[k] - ui0 - v_r[k];
                        if (cur < minv_r[k]) { minv_r[k] = cur; way_r[k] = j0; }
                        if (minv_r[k] < lv) { lv = minv_r[k]; kmin = k; }
                    }
                }
            }
            int pv_cand = sel5(p_r, kmin);      // own candidate, overlaps DPP
            int lj      = jbase + kmin;

            // 3. exact f32 min + owner (lowest lane == lowest j)
            float delta = bcast_f32(wave_min_f32(lv), 63);
            unsigned long long msk = __ballot(lv == delta);
            int owner = (int)__ffsll(msk) - 1;
            int j1    = __builtin_amdgcn_readlane(lj, owner);
            int i0n   = __builtin_amdgcn_readlane(pv_cand, owner);
            // 4. prefetch u[i0n] BEFORE delta update (i0n not in tree)
            float u_next = (i0n > 0) ? bcast_f32(u_val, i0n - 1) : 0.f;

            // 5. price updates
            if (inTree) u_val += delta;
            if (haveCols) {
                #pragma unroll
                for (int k = 0; k < CPL; ++k) {
                    if ((usedbits >> k) & 1) v_r[k]    -= delta;
                    else                     minv_r[k] -= delta;
                }
            }
            if (lane == owner) usedbits |= (1 << kmin);
            if (i0n == 0) { jfin = j1; break; }
            if (lane == i0n - 1) inTree = true;
            i0 = i0n; ui0 = u_next; j0 = j1;
        }

        // augment alternating path: p[jj] = p[way[jj]] (p[0] == i)
        int jj = jfin;
        while (jj) {
            int ow = (jj - 1) / CPL, kk = (jj - 1) % CPL;
            int jn = __builtin_amdgcn_readlane(sel5(way_r, kk), ow);
            int pn;
            if (jn == 0) {
                pn = i;
            } else {
                int ow2 = (jn - 1) / CPL, kk2 = (jn - 1) % CPL;
                pn = __builtin_amdgcn_readlane(sel5(p_r, kk2), ow2);
            }
            bool w = (lane == ow);
            p_r[0] = (w && kk == 0) ? pn : p_r[0];
            p_r[1] = (w && kk == 1) ? pn : p_r[1];
            p_r[2] = (w && kk == 2) ? pn : p_r[2];
            p_r[3] = (w && kk == 3) ? pn : p_r[3];
            p_r[4] = (w && kk == 4) ? pn : p_r[4];
            jj = jn;
        }
    }

    // fused loss partial: sum over this batch's 300 queries of (x[q,t]-logZ[q])
    double acc = 0.0;
    if (haveCols) {
        #pragma unroll
        for (int k = 0; k < CPL; ++k) {
            int q  = jbase - 1 + k;
            int pr = p_r[k];
            int t  = (pr > 0) ? pr - 1 : 0;
            int rg = b * NQ + q;
            float xv = x[(size_t)rg * NC + t];
            acc += (double)(xv - logZ[rg]);
        }
    }
    for (int off = 32; off; off >>= 1)
        acc += __shfl_xor(acc, off);

    if (lane == 0) {
        partial[b] = acc;
        __threadfence();
        int old = atomicAdd(done, 1);
        if (old == BS - 1) {
            __threadfence();                       // acquire others' partials
            double s = 0.0;
            #pragma unroll
            for (int k = 0; k < BS; ++k) s += partial[k];   // fixed order
            out[0] = (float)(-s / (double)NROW);
        }
    }
}

// ---------------------------------------------------------------------------
extern "C" void kernel_launch(void* const* d_in, const int* in_sizes, int n_in,
                              void* d_out, int out_size, void* d_ws, size_t ws_size,
                              hipStream_t stream) {
    const float* outputs = (const float*)d_in[0];
    const int*   labels  = (const int*)d_in[1];
    float*       out     = (float*)d_out;

    char* ws = (char*)d_ws;
    size_t off = 0;
    float*  logZ    = (float*)(ws + off);  off += (size_t)NROW * sizeof(float);
    float*  costQ   = (float*)(ws + off);  off += (size_t)NROW * NOBJ * sizeof(float);
    double* partial = (double*)(ws + off); off += (size_t)BS * sizeof(double);
    int*    flags   = (int*)  (ws + off);  off += 33 * sizeof(int);   // ready[32]+done

    hipMemsetAsync(flags, 0, 33 * sizeof(int), stream);
    fused_kernel<<<PBLK + BS, 256, 0, stream>>>(outputs, labels, logZ, costQ,
                                                partial, flags, flags + BS, out);
}

// Round 10
// 89.153 us; speedup vs baseline: 5.9652x; 5.9652x over previous
//
#include <hip/hip_runtime.h>
#include <hip/hip_bf16.h>
#include <cfloat>
#include <climits>

#define BS   32
#define NQ   300
#define NC   8192
#define NOBJ 64
#define NROW (BS * NQ)   // 9600
#define CPL  5           // cols per lane: lanes 0..59 own 5 contiguous cols
#define LPAD 65          // padded LDS row stride (words) for [j][t] cost tile

// ---------------------------------------------------------------------------
// helpers (f32 cross-lane: 1 readlane / 1 DPP per step)
// ---------------------------------------------------------------------------
__device__ __forceinline__ float bcast_f32(float v, int lane) {
    union { float f; int i; } c, r;
    c.f = v;
    r.i = __builtin_amdgcn_readlane(c.i, lane);
    return r.f;
}

template <int CTRL>
__device__ __forceinline__ float dpp_min_step_f32(float x) {
    union { float f; int i; } c, r;
    c.f = x;
    r.i = __builtin_amdgcn_update_dpp(c.i, c.i, CTRL, 0xF, 0xF, false);
    return fminf(x, r.f);
}

// full-wave64 min: result valid in lane 63 (validated rounds 3-8, absmax 0)
__device__ __forceinline__ float wave_min_f32(float x) {
    x = dpp_min_step_f32<0x111>(x);  // row_shr:1
    x = dpp_min_step_f32<0x112>(x);  // row_shr:2
    x = dpp_min_step_f32<0x114>(x);  // row_shr:4
    x = dpp_min_step_f32<0x118>(x);  // row_shr:8
    x = dpp_min_step_f32<0x142>(x);  // row_bcast:15
    x = dpp_min_step_f32<0x143>(x);  // row_bcast:31
    return x;
}

// compile-time-index select over a 5-reg int array (stays in VGPRs)
__device__ __forceinline__ int sel5(const int (&a)[CPL], int k) {
    int r = a[0];
    r = (k == 1) ? a[1] : r;
    r = (k == 2) ? a[2] : r;
    r = (k == 3) ? a[3] : r;
    r = (k == 4) ? a[4] : r;
    return r;
}

// ---------------------------------------------------------------------------
// Kernel 1 (fused): logZ per row + cost row costQ[row][t] = -exp(x - logZ).
// Gather of the 64 target logits issues BEFORE the streaming pass so the
// stream finds those lines cached and the gather latency hides under it.
// Block 0 zeroes out[0] for the hungarian kernel's atomic accumulation
// (kernel boundary = device-wide visibility).
// NOTE (round 9 lesson): do NOT fuse the matcher into this kernel — the
// cross-block handoff needs device-scope fences (buffer_wbl2 per block)
// and the consumer's 78KB LDS tile would be allocated to every block,
// collapsing stream occupancy. Measured 6x regression.
// ---------------------------------------------------------------------------
__global__ __launch_bounds__(256) void logz_cost_kernel(const float* __restrict__ x,
                                                        const int* __restrict__ labels,
                                                        float* __restrict__ logZ,
                                                        float* __restrict__ costQ,
                                                        float* __restrict__ out) {
    int wave = threadIdx.x >> 6;
    int lane = threadIdx.x & 63;
    int row  = blockIdx.x * 4 + wave;    // 2400 blocks * 4 = 9600 exactly
    int b    = row / NQ;

    if (blockIdx.x == 0 && threadIdx.x == 0) out[0] = 0.f;

    __shared__ int tgt_sh[4][NOBJ];
    // wave-local compact of this batch's labels (order-preserving)
    int lab = labels[b * NOBJ + lane];
    unsigned long long mask = __ballot(lab != 0);
    int nb  = __popcll(mask);
    int pos = __popcll(mask & ((1ull << lane) - 1ull));
    if (lab != 0) tgt_sh[wave][pos] = lab;   // own wave's slice; lgkm-ordered

    // gather target logits FIRST (independent; hides under the stream)
    float xv_g = 0.f;
    if (lane < nb) {
        int cls = tgt_sh[wave][lane];
        xv_g = x[(size_t)row * NC + cls];
    }

    const float4* p = (const float4*)(x + (size_t)row * NC);
    float s0 = 0.f, s1 = 0.f, s2 = 0.f, s3 = 0.f;
    #pragma unroll 8
    for (int k = 0; k < NC / 4 / 64; ++k) {   // 32 float4 per lane
        float4 v = p[lane + k * 64];
        s0 += __expf(v.x);
        s1 += __expf(v.y);
        s2 += __expf(v.z);
        s3 += __expf(v.w);
    }
    float s = (s0 + s1) + (s2 + s3);
    for (int off = 32; off; off >>= 1)
        s += __shfl_xor(s, off);
    float lz = logf(s);                        // all lanes hold it
    if (lane == 0) logZ[row] = lz;

    float c = (lane < nb) ? -__expf(xv_g - lz) : 0.f;
    costQ[(size_t)row * NOBJ + lane] = c;      // coalesced
}

// ---------------------------------------------------------------------------
// Kernel 2: JV assignment with row-reduction + greedy seeding, one block per
// batch; staging uses all 4 waves, solver runs on wave 0 only (no barriers
// after the staging sync -> early-return of waves 1-3 is safe).
// Fused loss: each block atomically adds its batch's CE contribution to out.
// Search/augment machinery identical to rounds 5-8 (f32 duals, absmax 0).
// ---------------------------------------------------------------------------
__global__ __launch_bounds__(256) void hungarian_kernel(const float* __restrict__ costQ,
                                                        const int* __restrict__ labels,
                                                        const float* __restrict__ x,
                                                        const float* __restrict__ logZ,
                                                        float* __restrict__ out) {
    int b    = blockIdx.x;
    int tid  = threadIdx.x;
    int lane = tid & 63;
    int wid  = tid >> 6;

    __shared__ float cst[NQ * LPAD];   // 300*65*4 = 78 KB, layout [j][t]
    __shared__ int   col_owner[NQ];    // greedy seeding scratch

    int lab = 0, n = 0;
    if (wid == 0) {
        lab = labels[b * NOBJ + lane];
        n   = __popcll(__ballot(lab != 0));
    }

    // stage costQ -> LDS transpose-pad with all 256 threads
    {
        const float4* src = (const float4*)(costQ + (size_t)b * NQ * NOBJ);
        #pragma unroll
        for (int t = 0; t < 19; ++t) {   // 19*256 >= 4800
            int idx = tid + t * 256;
            if (idx < NQ * NOBJ / 4) {
                float4 v = src[idx];
                int e  = 4 * idx;
                int j  = e >> 6;        // query index
                int t0 = e & 63;        // target index (multiple of 4)
                float* d = &cst[j * LPAD + t0];
                d[0] = v.x; d[1] = v.y; d[2] = v.z; d[3] = v.w;
            }
        }
    }
    for (int j = tid; j < NQ; j += 256) col_owner[j] = INT_MAX;
    __syncthreads();
    if (wid != 0) return;               // solver is wave 0 only; no barriers below

    const int  jbase    = lane * CPL + 1;
    const bool haveCols = (lane < 60);

    // ---- row reduction: lane L = row L+1; u = min_j cost[row][j] ----------
    float rmin = INFINITY;
    int   rarg = 0;
    if (lane < n) {
        #pragma unroll 4
        for (int j = 0; j < NQ; ++j) {
            float cv = cst[j * LPAD + lane];   // banks conflict-free
            if (cv < rmin) { rmin = cv; rarg = j; }   // first-index on ties
        }
    }
    float u_val = (lane < n) ? rmin : 0.f;

    // ---- greedy seeding: lowest row wins each column (wave-local atomics) --
    if (lane < n) atomicMin(&col_owner[rarg], lane);
    bool won = (lane < n) && (col_owner[rarg] == lane);
    if ((lane < n) && !won) atomicCAS(&col_owner[rarg], lane, INT_MAX);

    float v_r[CPL], minv_r[CPL];
    int   p_r[CPL], way_r[CPL];
    #pragma unroll
    for (int k = 0; k < CPL; ++k) {
        v_r[k] = 0.f; way_r[k] = 0;
        int own = haveCols ? col_owner[jbase - 1 + k] : INT_MAX;
        p_r[k] = (own != INT_MAX) ? own + 1 : 0;
    }

    unsigned long long todo = __ballot((lane < n) && !won);

    while (todo) {
        int i = (int)__ffsll(todo);        // row index (1-based)
        todo &= todo - 1;

        #pragma unroll
        for (int k = 0; k < CPL; ++k) minv_r[k] = INFINITY;
        int  usedbits = 0;
        bool inTree   = (lane == i - 1);   // virtual col 0: p[0]=i
        int  i0 = i, j0 = 0, jfin;
        float ui0 = bcast_f32(u_val, i - 1);

        while (true) {
            // 1. issue LDS loads ASAP (addresses depend only on i0)
            int cbase = i0 - 1;
            float ld[CPL];
            #pragma unroll
            for (int k = 0; k < CPL; ++k)
                ld[k] = cst[(jbase - 1 + k) * LPAD + cbase];

            // 2. scan: update minv, track per-lane (lv, kmin); k asc = first-j
            float lv = INFINITY;
            int   kmin = 0;
            if (haveCols) {
                #pragma unroll
                for (int k = 0; k < CPL; ++k) {
                    if (!((usedbits >> k) & 1)) {
                        float cur = ld[k] - ui0 - v_r[k];
                        if (cur < minv_r[k]) { minv_r[k] = cur; way_r[k] = j0; }
                        if (minv_r[k] < lv) { lv = minv_r[k]; kmin = k; }
                    }
                }
            }
            int pv_cand = sel5(p_r, kmin);      // own candidate, overlaps DPP
            int lj      = jbase + kmin;

            // 3. exact f32 min + owner (lowest lane == lowest j)
            float delta = bcast_f32(wave_min_f32(lv), 63);
            unsigned long long msk = __ballot(lv == delta);
            int owner = (int)__ffsll(msk) - 1;
            int j1    = __builtin_amdgcn_readlane(lj, owner);
            int i0n   = __builtin_amdgcn_readlane(pv_cand, owner);
            // 4. prefetch u[i0n] BEFORE delta update (i0n not in tree)
            float u_next = (i0n > 0) ? bcast_f32(u_val, i0n - 1) : 0.f;

            // 5. price updates
            if (inTree) u_val += delta;
            if (haveCols) {
                #pragma unroll
                for (int k = 0; k < CPL; ++k) {
                    if ((usedbits >> k) & 1) v_r[k]    -= delta;
                    else                     minv_r[k] -= delta;
                }
            }
            if (lane == owner) usedbits |= (1 << kmin);
            if (i0n == 0) { jfin = j1; break; }
            if (lane == i0n - 1) inTree = true;
            i0 = i0n; ui0 = u_next; j0 = j1;
        }

        // augment alternating path: p[jj] = p[way[jj]] (p[0] == i)
        int jj = jfin;
        while (jj) {
            int ow = (jj - 1) / CPL, kk = (jj - 1) % CPL;
            int jn = __builtin_amdgcn_readlane(sel5(way_r, kk), ow);
            int pn;
            if (jn == 0) {
                pn = i;
            } else {
                int ow2 = (jn - 1) / CPL, kk2 = (jn - 1) % CPL;
                pn = __builtin_amdgcn_readlane(sel5(p_r, kk2), ow2);
            }
            bool w = (lane == ow);
            p_r[0] = (w && kk == 0) ? pn : p_r[0];
            p_r[1] = (w && kk == 1) ? pn : p_r[1];
            p_r[2] = (w && kk == 2) ? pn : p_r[2];
            p_r[3] = (w && kk == 3) ? pn : p_r[3];
            p_r[4] = (w && kk == 4) ? pn : p_r[4];
            jj = jn;
        }
    }

    // fused loss: sum over this batch's 300 queries of (x[q,t]-logZ[q]),
    // then one atomic accumulate of the scaled contribution into out[0].
    double acc = 0.0;
    if (haveCols) {
        #pragma unroll
        for (int k = 0; k < CPL; ++k) {
            int q  = jbase - 1 + k;
            int pr = p_r[k];
            int t  = (pr > 0) ? pr - 1 : 0;
            int rg = b * NQ + q;
            float xv = x[(size_t)rg * NC + t];
            acc += (double)(xv - logZ[rg]);
        }
    }
    for (int off = 32; off; off >>= 1)
        acc += __shfl_xor(acc, off);
    if (lane == 0) atomicAdd(out, (float)(-acc / (double)NROW));
}

// ---------------------------------------------------------------------------
extern "C" void kernel_launch(void* const* d_in, const int* in_sizes, int n_in,
                              void* d_out, int out_size, void* d_ws, size_t ws_size,
                              hipStream_t stream) {
    const float* outputs = (const float*)d_in[0];
    const int*   labels  = (const int*)d_in[1];
    float*       out     = (float*)d_out;

    char* ws = (char*)d_ws;
    size_t off = 0;
    float* logZ  = (float*)(ws + off); off += (size_t)NROW * sizeof(float);
    float* costQ = (float*)(ws + off); off += (size_t)NROW * NOBJ * sizeof(float);

    logz_cost_kernel<<<NROW / 4, 256, 0, stream>>>(outputs, labels, logZ, costQ, out);
    hungarian_kernel<<<BS, 256, 0, stream>>>(costQ, labels, outputs, logZ, out);
}

// Round 11
// 80.651 us; speedup vs baseline: 6.5940x; 1.1054x over previous
//
#include <hip/hip_runtime.h>
#include <hip/hip_bf16.h>
#include <cfloat>
#include <climits>

#define BS   32
#define NQ   300
#define NC   8192
#define NOBJ 64
#define NROW (BS * NQ)   // 9600
#define CPL  5           // cols per lane: lanes 0..59 own 5 contiguous cols
#define LPAD 65          // padded LDS row stride (words) for [j][t] cost tile

// ---------------------------------------------------------------------------
// helpers (f32 cross-lane: 1 readlane / 1 DPP per step)
// ---------------------------------------------------------------------------
__device__ __forceinline__ float bcast_f32(float v, int lane) {
    union { float f; int i; } c, r;
    c.f = v;
    r.i = __builtin_amdgcn_readlane(c.i, lane);
    return r.f;
}

template <int CTRL>
__device__ __forceinline__ float dpp_min_step_f32(float x) {
    union { float f; int i; } c, r;
    c.f = x;
    r.i = __builtin_amdgcn_update_dpp(c.i, c.i, CTRL, 0xF, 0xF, false);
    return fminf(x, r.f);
}

// full-wave64 min: result valid in lane 63 (validated rounds 3-10, absmax 0)
__device__ __forceinline__ float wave_min_f32(float x) {
    x = dpp_min_step_f32<0x111>(x);  // row_shr:1
    x = dpp_min_step_f32<0x112>(x);  // row_shr:2
    x = dpp_min_step_f32<0x114>(x);  // row_shr:4
    x = dpp_min_step_f32<0x118>(x);  // row_shr:8
    x = dpp_min_step_f32<0x142>(x);  // row_bcast:15
    x = dpp_min_step_f32<0x143>(x);  // row_bcast:31
    return x;
}

// compile-time-index select over a 5-reg int array (stays in VGPRs)
__device__ __forceinline__ int sel5(const int (&a)[CPL], int k) {
    int r = a[0];
    r = (k == 1) ? a[1] : r;
    r = (k == 2) ? a[2] : r;
    r = (k == 3) ? a[3] : r;
    r = (k == 4) ? a[4] : r;
    return r;
}

// ---------------------------------------------------------------------------
// Kernel 1 (fused): logZ per row + cost row costQ[row][t] = -exp(x - logZ).
// (unchanged from round 10; stream is within ~10% of the HBM floor)
// ---------------------------------------------------------------------------
__global__ __launch_bounds__(256) void logz_cost_kernel(const float* __restrict__ x,
                                                        const int* __restrict__ labels,
                                                        float* __restrict__ logZ,
                                                        float* __restrict__ costQ,
                                                        float* __restrict__ out) {
    int wave = threadIdx.x >> 6;
    int lane = threadIdx.x & 63;
    int row  = blockIdx.x * 4 + wave;    // 2400 blocks * 4 = 9600 exactly
    int b    = row / NQ;

    if (blockIdx.x == 0 && threadIdx.x == 0) out[0] = 0.f;

    __shared__ int tgt_sh[4][NOBJ];
    int lab = labels[b * NOBJ + lane];
    unsigned long long mask = __ballot(lab != 0);
    int nb  = __popcll(mask);
    int pos = __popcll(mask & ((1ull << lane) - 1ull));
    if (lab != 0) tgt_sh[wave][pos] = lab;   // own wave's slice; lgkm-ordered

    float xv_g = 0.f;
    if (lane < nb) {
        int cls = tgt_sh[wave][lane];
        xv_g = x[(size_t)row * NC + cls];
    }

    const float4* p = (const float4*)(x + (size_t)row * NC);
    float s0 = 0.f, s1 = 0.f, s2 = 0.f, s3 = 0.f;
    #pragma unroll 8
    for (int k = 0; k < NC / 4 / 64; ++k) {   // 32 float4 per lane
        float4 v = p[lane + k * 64];
        s0 += __expf(v.x);
        s1 += __expf(v.y);
        s2 += __expf(v.z);
        s3 += __expf(v.w);
    }
    float s = (s0 + s1) + (s2 + s3);
    for (int off = 32; off; off >>= 1)
        s += __shfl_xor(s, off);
    float lz = logf(s);
    if (lane == 0) logZ[row] = lz;

    float c = (lane < nb) ? -__expf(xv_g - lz) : 0.f;
    costQ[(size_t)row * NOBJ + lane] = c;      // coalesced
}

// ---------------------------------------------------------------------------
// Kernel 2: JV assignment with DOUBLE reduction (column then row) + greedy
// seeding, one block per batch; solver on wave 0.
//   v[j] = min_i c[i][j]           (free columns get tight edges too ->
//   u[i] = min_j (c[i][j] - v[j])   Dijkstra trees shrink from ~45 to ~10)
// Greedy-seeded matches are tight (row argmin has reduced cost 0) ->
// complementary slackness holds -> exact optimum -> same unique assignment.
// Search/augment machinery identical to rounds 5-10 (f32 duals, absmax 0).
// ---------------------------------------------------------------------------
__global__ __launch_bounds__(256) void hungarian_kernel(const float* __restrict__ costQ,
                                                        const int* __restrict__ labels,
                                                        const float* __restrict__ x,
                                                        const float* __restrict__ logZ,
                                                        float* __restrict__ out) {
    int b    = blockIdx.x;
    int tid  = threadIdx.x;
    int lane = tid & 63;
    int wid  = tid >> 6;

    __shared__ float cst[NQ * LPAD];   // 300*65*4 = 78 KB, layout [j][t]
    __shared__ float v_sh[NQ];         // column-reduction duals
    __shared__ int   col_owner[NQ];    // greedy seeding scratch

    int lab = 0, n = 0;
    if (wid == 0) {
        lab = labels[b * NOBJ + lane];
        n   = __popcll(__ballot(lab != 0));
    }

    // stage costQ -> LDS transpose-pad with all 256 threads
    {
        const float4* src = (const float4*)(costQ + (size_t)b * NQ * NOBJ);
        #pragma unroll
        for (int t = 0; t < 19; ++t) {   // 19*256 >= 4800
            int idx = tid + t * 256;
            if (idx < NQ * NOBJ / 4) {
                float4 v = src[idx];
                int e  = 4 * idx;
                int j  = e >> 6;        // query index
                int t0 = e & 63;        // target index (multiple of 4)
                float* d = &cst[j * LPAD + t0];
                d[0] = v.x; d[1] = v.y; d[2] = v.z; d[3] = v.w;
            }
        }
    }
    for (int j = tid; j < NQ; j += 256) col_owner[j] = INT_MAX;
    __syncthreads();

    // ---- column reduction with all 4 waves: v[j] = min_t cst[j][t] --------
    // (pads at t>=n are 0.f; real costs are strictly negative, so pads never
    //  win unless n==0, in which case v=0 and there is nothing to solve)
    for (int j = tid; j < NQ; j += 256) {
        float mn = INFINITY;
        #pragma unroll 8
        for (int t = 0; t < NOBJ; ++t)
            mn = fminf(mn, cst[j * LPAD + t]);
        v_sh[j] = mn;
    }
    __syncthreads();
    if (wid != 0) return;               // solver is wave 0 only; no barriers below

    const int  jbase    = lane * CPL + 1;
    const bool haveCols = (lane < 60);

    // ---- row reduction on reduced costs: u[i] = min_j (c[i][j] - v[j]) ----
    float rmin = INFINITY;
    int   rarg = 0;
    if (lane < n) {
        #pragma unroll 4
        for (int j = 0; j < NQ; ++j) {
            float red = cst[j * LPAD + lane] - v_sh[j];  // v_sh[j]: broadcast
            if (red < rmin) { rmin = red; rarg = j; }    // first-index on ties
        }
    }
    float u_val = (lane < n) ? rmin : 0.f;

    // ---- greedy seeding: lowest row wins each column (wave-local atomics) --
    if (lane < n) atomicMin(&col_owner[rarg], lane);
    bool won = (lane < n) && (col_owner[rarg] == lane);
    if ((lane < n) && !won) atomicCAS(&col_owner[rarg], lane, INT_MAX);

    float v_r[CPL], minv_r[CPL];
    int   p_r[CPL], way_r[CPL];
    #pragma unroll
    for (int k = 0; k < CPL; ++k) {
        way_r[k] = 0;
        v_r[k]   = haveCols ? v_sh[jbase - 1 + k] : 0.f;
        int own  = haveCols ? col_owner[jbase - 1 + k] : INT_MAX;
        p_r[k]   = (own != INT_MAX) ? own + 1 : 0;
    }

    unsigned long long todo = __ballot((lane < n) && !won);

    while (todo) {
        int i = (int)__ffsll(todo);        // row index (1-based)
        todo &= todo - 1;

        #pragma unroll
        for (int k = 0; k < CPL; ++k) minv_r[k] = INFINITY;
        int  usedbits = 0;
        bool inTree   = (lane == i - 1);   // virtual col 0: p[0]=i
        int  i0 = i, j0 = 0, jfin;
        float ui0 = bcast_f32(u_val, i - 1);

        while (true) {
            // 1. issue LDS loads ASAP (addresses depend only on i0)
            int cbase = i0 - 1;
            float ld[CPL];
            #pragma unroll
            for (int k = 0; k < CPL; ++k)
                ld[k] = cst[(jbase - 1 + k) * LPAD + cbase];

            // 2. scan: update minv, track per-lane (lv, kmin); k asc = first-j
            float lv = INFINITY;
            int   kmin = 0;
            if (haveCols) {
                #pragma unroll
                for (int k = 0; k < CPL; ++k) {
                    if (!((usedbits >> k) & 1)) {
                        float cur = ld[k] - ui0 - v_r[k];
                        if (cur < minv_r[k]) { minv_r[k] = cur; way_r[k] = j0; }
                        if (minv_r[k] < lv) { lv = minv_r[k]; kmin = k; }
                    }
                }
            }
            int pv_cand = sel5(p_r, kmin);      // own candidate, overlaps DPP
            int lj      = jbase + kmin;

            // 3. exact f32 min + owner (lowest lane == lowest j)
            float delta = bcast_f32(wave_min_f32(lv), 63);
            unsigned long long msk = __ballot(lv == delta);
            int owner = (int)__ffsll(msk) - 1;
            int j1    = __builtin_amdgcn_readlane(lj, owner);
            int i0n   = __builtin_amdgcn_readlane(pv_cand, owner);
            // 4. prefetch u[i0n] BEFORE delta update (i0n not in tree)
            float u_next = (i0n > 0) ? bcast_f32(u_val, i0n - 1) : 0.f;

            // 5. price updates
            if (inTree) u_val += delta;
            if (haveCols) {
                #pragma unroll
                for (int k = 0; k < CPL; ++k) {
                    if ((usedbits >> k) & 1) v_r[k]    -= delta;
                    else                     minv_r[k] -= delta;
                }
            }
            if (lane == owner) usedbits |= (1 << kmin);
            if (i0n == 0) { jfin = j1; break; }
            if (lane == i0n - 1) inTree = true;
            i0 = i0n; ui0 = u_next; j0 = j1;
        }

        // augment alternating path: p[jj] = p[way[jj]] (p[0] == i)
        int jj = jfin;
        while (jj) {
            int ow = (jj - 1) / CPL, kk = (jj - 1) % CPL;
            int jn = __builtin_amdgcn_readlane(sel5(way_r, kk), ow);
            int pn;
            if (jn == 0) {
                pn = i;
            } else {
                int ow2 = (jn - 1) / CPL, kk2 = (jn - 1) % CPL;
                pn = __builtin_amdgcn_readlane(sel5(p_r, kk2), ow2);
            }
            bool w = (lane == ow);
            p_r[0] = (w && kk == 0) ? pn : p_r[0];
            p_r[1] = (w && kk == 1) ? pn : p_r[1];
            p_r[2] = (w && kk == 2) ? pn : p_r[2];
            p_r[3] = (w && kk == 3) ? pn : p_r[3];
            p_r[4] = (w && kk == 4) ? pn : p_r[4];
            jj = jn;
        }
    }

    // fused loss: sum over this batch's 300 queries of (x[q,t]-logZ[q]),
    // then one atomic accumulate of the scaled contribution into out[0].
    double acc = 0.0;
    if (haveCols) {
        #pragma unroll
        for (int k = 0; k < CPL; ++k) {
            int q  = jbase - 1 + k;
            int pr = p_r[k];
            int t  = (pr > 0) ? pr - 1 : 0;
            int rg = b * NQ + q;
            float xv = x[(size_t)rg * NC + t];
            acc += (double)(xv - logZ[rg]);
        }
    }
    for (int off = 32; off; off >>= 1)
        acc += __shfl_xor(acc, off);
    if (lane == 0) atomicAdd(out, (float)(-acc / (double)NROW));
}

// ---------------------------------------------------------------------------
extern "C" void kernel_launch(void* const* d_in, const int* in_sizes, int n_in,
                              void* d_out, int out_size, void* d_ws, size_t ws_size,
                              hipStream_t stream) {
    const float* outputs = (const float*)d_in[0];
    const int*   labels  = (const int*)d_in[1];
    float*       out     = (float*)d_out;

    char* ws = (char*)d_ws;
    size_t off = 0;
    float* logZ  = (float*)(ws + off); off += (size_t)NROW * sizeof(float);
    float* costQ = (float*)(ws + off); off += (size_t)NROW * NOBJ * sizeof(float);

    logz_cost_kernel<<<NROW / 4, 256, 0, stream>>>(outputs, labels, logZ, costQ, out);
    hungarian_kernel<<<BS, 256, 0, stream>>>(costQ, labels, outputs, logZ, out);
}